// Round 1
// baseline (535.106 us; speedup 1.0000x reference)
//
#include <hip/hip_runtime.h>
#include <hip/hip_bf16.h>
#include <math.h>

#define NEG_SLOPE 0.2f

// ---------------------------------------------------------------------------
// CSR build: histogram -> block scan -> scatter fill
// ---------------------------------------------------------------------------
__global__ void hist_k(const int* __restrict__ ei, int E, int n, int* __restrict__ deg) {
    int e = blockIdx.x * 256 + threadIdx.x;
    int ET = E + n;
    if (e >= ET) return;
    int d = (e < E) ? ei[E + e] : (e - E);
    atomicAdd(&deg[d], 1);
}

__global__ void scan1_k(const int* __restrict__ deg, int* __restrict__ incl,
                        int* __restrict__ bsums, int n) {
    __shared__ int s[256];
    int tid = threadIdx.x;
    int i = blockIdx.x * 256 + tid;
    int v = (i < n) ? deg[i] : 0;
    s[tid] = v;
    __syncthreads();
    for (int off = 1; off < 256; off <<= 1) {
        int t = (tid >= off) ? s[tid - off] : 0;
        __syncthreads();
        s[tid] += t;
        __syncthreads();
    }
    if (i < n) incl[i] = s[tid];
    if (tid == 255) bsums[blockIdx.x] = s[255];
}

__global__ void scan2_k(int* __restrict__ bsums, int nch) {
    __shared__ int s[256];
    int tid = threadIdx.x;
    int v = (tid < nch) ? bsums[tid] : 0;
    int orig = v;
    s[tid] = v;
    __syncthreads();
    for (int off = 1; off < 256; off <<= 1) {
        int t = (tid >= off) ? s[tid - off] : 0;
        __syncthreads();
        s[tid] += t;
        __syncthreads();
    }
    if (tid < nch) bsums[tid] = s[tid] - orig;  // exclusive
}

__global__ void scan3_k(int* __restrict__ offsets, int* __restrict__ cursor,
                        const int* __restrict__ bsums, int n, int total) {
    int i = blockIdx.x * 256 + threadIdx.x;
    if (i < n) {
        int excl = offsets[i] - cursor[i] + bsums[i >> 8];
        offsets[i] = excl;
        cursor[i]  = excl;
    }
    if (i == 0 && blockIdx.x == 0) offsets[n] = total;
}

__global__ void fill_k(const int* __restrict__ ei, int E, int n,
                       int* __restrict__ cursor, int* __restrict__ csr) {
    int e = blockIdx.x * 256 + threadIdx.x;
    int ET = E + n;
    if (e >= ET) return;
    int s, d;
    if (e < E) { s = ei[e]; d = ei[E + e]; }
    else       { s = e - E; d = e - E; }
    int pos = atomicAdd(&cursor[d], 1);
    csr[pos] = s;
}

// ---------------------------------------------------------------------------
// fp32 tiled GEMM: C[M,Nc] = A[M,K] @ B[K,Nc]; Nc % 64 == 0, K % 32 == 0
// ---------------------------------------------------------------------------
__global__ __launch_bounds__(256) void gemm64_k(const float* __restrict__ A,
                                                const float* __restrict__ B,
                                                float* __restrict__ Cc,
                                                int M, int K, int Nc) {
    __shared__ float As[32][64];  // [k][m]
    __shared__ float Bs[32][64];  // [k][n]
    int tid = threadIdx.x;
    int tx = tid & 15, ty = tid >> 4;
    int m0 = blockIdx.x << 6, n0 = blockIdx.y << 6;
    float c[4][4] = {};
    for (int k0 = 0; k0 < K; k0 += 32) {
#pragma unroll
        for (int l = 0; l < 2; l++) {
            int f = tid + (l << 8);          // 0..511
            // A tile: 64 rows x 8 float4
            int r = f >> 3, kq = f & 7;
            int gr = m0 + r;
            float4 av = make_float4(0.f, 0.f, 0.f, 0.f);
            if (gr < M) av = *(const float4*)(A + (size_t)gr * K + k0 + (kq << 2));
            As[(kq << 2) + 0][r] = av.x;
            As[(kq << 2) + 1][r] = av.y;
            As[(kq << 2) + 2][r] = av.z;
            As[(kq << 2) + 3][r] = av.w;
            // B tile: 32 rows x 16 float4
            int kk = f >> 4, c4 = f & 15;
            *(float4*)&Bs[kk][c4 << 2] =
                *(const float4*)(B + (size_t)(k0 + kk) * Nc + n0 + (c4 << 2));
        }
        __syncthreads();
#pragma unroll
        for (int kk = 0; kk < 32; kk++) {
            float4 a = *(const float4*)&As[kk][ty << 2];
            float4 b = *(const float4*)&Bs[kk][tx << 2];
            float av4[4] = {a.x, a.y, a.z, a.w};
            float bv4[4] = {b.x, b.y, b.z, b.w};
#pragma unroll
            for (int i = 0; i < 4; i++)
#pragma unroll
                for (int j = 0; j < 4; j++)
                    c[i][j] = fmaf(av4[i], bv4[j], c[i][j]);
        }
        __syncthreads();
    }
#pragma unroll
    for (int i = 0; i < 4; i++) {
        int gr = m0 + (ty << 2) + i;
        if (gr < M) {
            float4 o = make_float4(c[i][0], c[i][1], c[i][2], c[i][3]);
            *(float4*)(Cc + (size_t)gr * Nc + n0 + (tx << 2)) = o;
        }
    }
}

// ---------------------------------------------------------------------------
// attention prep: as[i] = h[i,:]·a_src, ad[i] = h[i,:]·a_dst   (wave per row)
// ---------------------------------------------------------------------------
template <int D>
__global__ void prep_k(const float* __restrict__ h, const float* __restrict__ avs,
                       const float* __restrict__ avd, float* __restrict__ as_o,
                       float* __restrict__ ad_o, int n) {
    int wid = (blockIdx.x << 2) + (threadIdx.x >> 6);
    int lane = threadIdx.x & 63;
    if (wid >= n) return;
    const float* row = h + (size_t)wid * D;
    float s = 0.f, d = 0.f;
#pragma unroll
    for (int u = 0; u < D / 64; u++) {
        float hv = row[u * 64 + lane];
        s = fmaf(hv, avs[u * 64 + lane], s);
        d = fmaf(hv, avd[u * 64 + lane], d);
    }
#pragma unroll
    for (int o = 32; o; o >>= 1) {
        s += __shfl_xor(s, o);
        d += __shfl_xor(d, o);
    }
    if (lane == 0) { as_o[wid] = s; ad_o[wid] = d; }
}

// ---------------------------------------------------------------------------
// fused per-node softmax + aggregation (wave per node)
// ---------------------------------------------------------------------------
template <int D, bool DO_ELU>
__global__ void agg_k(const int* __restrict__ offs, const int* __restrict__ csr,
                      const float* __restrict__ asb, const float* __restrict__ adb,
                      const float* __restrict__ h, const float* __restrict__ bias,
                      float* __restrict__ out, int n) {
    int wid = (blockIdx.x << 2) + (threadIdx.x >> 6);
    int lane = threadIdx.x & 63;
    if (wid >= n) return;
    int beg = offs[wid], end = offs[wid + 1];
    float adi = adb[wid];

    float m = -INFINITY;
    for (int e = beg + lane; e < end; e += 64) {
        float v = asb[csr[e]] + adi;
        v = v > 0.f ? v : NEG_SLOPE * v;
        m = fmaxf(m, v);
    }
#pragma unroll
    for (int o = 32; o; o >>= 1) m = fmaxf(m, __shfl_xor(m, o));

    float ssum = 0.f;
    for (int e = beg + lane; e < end; e += 64) {
        float v = asb[csr[e]] + adi;
        v = v > 0.f ? v : NEG_SLOPE * v;
        ssum += __expf(v - m);
    }
#pragma unroll
    for (int o = 32; o; o >>= 1) ssum += __shfl_xor(ssum, o);
    float inv = 1.f / ssum;

    constexpr int U = D / 64;
    float acc[U];
#pragma unroll
    for (int u = 0; u < U; u++) acc[u] = 0.f;

    for (int e = beg; e < end; ++e) {
        int j = csr[e];
        float v = asb[j] + adi;
        v = v > 0.f ? v : NEG_SLOPE * v;
        float w = __expf(v - m);
        if constexpr (U == 4) {
            const float4 hv = *(const float4*)(h + (size_t)j * D + (lane << 2));
            acc[0] = fmaf(w, hv.x, acc[0]);
            acc[1] = fmaf(w, hv.y, acc[1]);
            acc[2] = fmaf(w, hv.z, acc[2]);
            acc[3] = fmaf(w, hv.w, acc[3]);
        } else {
            acc[0] = fmaf(w, h[(size_t)j * D + lane], acc[0]);
        }
    }

    if constexpr (U == 4) {
        float4 o;
        float* po = &o.x;
#pragma unroll
        for (int u = 0; u < 4; u++) {
            float t = acc[u] * inv + bias[(lane << 2) + u];
            if (DO_ELU) t = t > 0.f ? t : expm1f(t);
            po[u] = t;
        }
        *(float4*)(out + (size_t)wid * D + (lane << 2)) = o;
    } else {
        float t = acc[0] * inv + bias[lane];
        if (DO_ELU) t = t > 0.f ? t : expm1f(t);
        out[(size_t)wid * D + lane] = t;
    }
}

// ---------------------------------------------------------------------------
// layer 3: h3 = out2 @ W3 (64->1) fused with logit pieces
// ---------------------------------------------------------------------------
__global__ void l3_prep_k(const float* __restrict__ o2, const float* __restrict__ W3,
                          const float* __restrict__ as3, const float* __restrict__ ad3,
                          float* __restrict__ h3, float* __restrict__ asb,
                          float* __restrict__ adb, int n) {
    int wid = (blockIdx.x << 2) + (threadIdx.x >> 6);
    int lane = threadIdx.x & 63;
    if (wid >= n) return;
    float t = o2[(size_t)wid * 64 + lane] * W3[lane];
#pragma unroll
    for (int o = 32; o; o >>= 1) t += __shfl_xor(t, o);
    if (lane == 0) {
        h3[wid]  = t;
        asb[wid] = t * as3[0];
        adb[wid] = t * ad3[0];
    }
}

__global__ void agg3_k(const int* __restrict__ offs, const int* __restrict__ csr,
                       const float* __restrict__ asb, const float* __restrict__ adb,
                       const float* __restrict__ h3, const float* __restrict__ b3,
                       float* __restrict__ out, int n) {
    int wid = (blockIdx.x << 2) + (threadIdx.x >> 6);
    int lane = threadIdx.x & 63;
    if (wid >= n) return;
    int beg = offs[wid], end = offs[wid + 1];
    float adi = adb[wid];

    float m = -INFINITY;
    for (int e = beg + lane; e < end; e += 64) {
        float v = asb[csr[e]] + adi;
        v = v > 0.f ? v : NEG_SLOPE * v;
        m = fmaxf(m, v);
    }
#pragma unroll
    for (int o = 32; o; o >>= 1) m = fmaxf(m, __shfl_xor(m, o));

    float ssum = 0.f, acc = 0.f;
    for (int e = beg + lane; e < end; e += 64) {
        int j = csr[e];
        float v = asb[j] + adi;
        v = v > 0.f ? v : NEG_SLOPE * v;
        float w = __expf(v - m);
        ssum += w;
        acc = fmaf(w, h3[j], acc);
    }
#pragma unroll
    for (int o = 32; o; o >>= 1) {
        ssum += __shfl_xor(ssum, o);
        acc  += __shfl_xor(acc, o);
    }
    if (lane == 0) out[wid] = acc / ssum + b3[0];
}

// ---------------------------------------------------------------------------
extern "C" void kernel_launch(void* const* d_in, const int* in_sizes, int n_in,
                              void* d_out, int out_size, void* d_ws, size_t ws_size,
                              hipStream_t stream) {
    const float* x   = (const float*)d_in[0];
    const int*   ei  = (const int*)d_in[1];
    const float* W1  = (const float*)d_in[2];
    const float* as1 = (const float*)d_in[3];
    const float* ad1 = (const float*)d_in[4];
    const float* b1  = (const float*)d_in[5];
    const float* W2  = (const float*)d_in[6];
    const float* as2 = (const float*)d_in[7];
    const float* ad2 = (const float*)d_in[8];
    const float* b2  = (const float*)d_in[9];
    const float* W3  = (const float*)d_in[10];
    const float* as3 = (const float*)d_in[11];
    const float* ad3 = (const float*)d_in[12];
    const float* b3  = (const float*)d_in[13];

    const int d1 = in_sizes[3];                    // 256
    const int C  = in_sizes[2] / d1;               // 128
    const int N  = in_sizes[0] / C;                // 50000
    const int E  = in_sizes[1] / 2;                // 800000
    const int d2 = in_sizes[7];                    // 64
    const int ET = E + N;                          // 850000

    // workspace carve-out
    char* p = (char*)d_ws;
    auto alloc = [&](size_t bytes) -> void* {
        void* q = (void*)p;
        p += (bytes + 255) & ~(size_t)255;
        return q;
    };
    int*   offsets = (int*)alloc(sizeof(int) * (size_t)(N + 1));
    int*   cursor  = (int*)alloc(sizeof(int) * (size_t)N);
    int*   bsums   = (int*)alloc(sizeof(int) * 256);
    int*   csr     = (int*)alloc(sizeof(int) * (size_t)ET);
    float* asb     = (float*)alloc(sizeof(float) * (size_t)N);
    float* adb     = (float*)alloc(sizeof(float) * (size_t)N);
    float* hbuf    = (float*)alloc(sizeof(float) * (size_t)N * d1);
    float* obuf    = (float*)alloc(sizeof(float) * (size_t)N * d1);

    const int eb  = (ET + 255) / 256;
    const int nch = (N + 255) / 256;
    const int wb  = (N + 3) / 4;     // 4 waves (nodes) per 256-thread block

    // ---- CSR build ----
    hipMemsetAsync(cursor, 0, sizeof(int) * (size_t)N, stream);
    hist_k<<<eb, 256, 0, stream>>>(ei, E, N, cursor);
    scan1_k<<<nch, 256, 0, stream>>>(cursor, offsets, bsums, N);
    scan2_k<<<1, 256, 0, stream>>>(bsums, nch);
    scan3_k<<<nch, 256, 0, stream>>>(offsets, cursor, bsums, N, ET);
    fill_k<<<eb, 256, 0, stream>>>(ei, E, N, cursor, csr);

    // ---- layer 1: 128 -> 256, ELU ----
    {
        dim3 g((N + 63) / 64, d1 / 64);
        gemm64_k<<<g, 256, 0, stream>>>(x, W1, hbuf, N, C, d1);
        prep_k<256><<<wb, 256, 0, stream>>>(hbuf, as1, ad1, asb, adb, N);
        agg_k<256, true><<<wb, 256, 0, stream>>>(offsets, csr, asb, adb, hbuf, b1, obuf, N);
    }
    // ---- layer 2: 256 -> 64, ELU ----
    {
        dim3 g((N + 63) / 64, d2 / 64);
        gemm64_k<<<g, 256, 0, stream>>>(obuf, W2, hbuf, N, d1, d2);
        prep_k<64><<<wb, 256, 0, stream>>>(hbuf, as2, ad2, asb, adb, N);
        agg_k<64, true><<<wb, 256, 0, stream>>>(offsets, csr, asb, adb, hbuf, b2, obuf, N);
    }
    // ---- layer 3: 64 -> 1 ----
    {
        l3_prep_k<<<wb, 256, 0, stream>>>(obuf, W3, as3, ad3, hbuf, asb, adb, N);
        agg3_k<<<wb, 256, 0, stream>>>(offsets, csr, asb, adb, hbuf, b3, (float*)d_out, N);
    }
}

// Round 2
// 470.923 us; speedup vs baseline: 1.1363x; 1.1363x over previous
//
#include <hip/hip_runtime.h>
#include <hip/hip_bf16.h>
#include <math.h>

#define NEG_SLOPE 0.2f

// ---------------------------------------------------------------------------
// CSR build: histogram -> block scan -> scatter fill
// ---------------------------------------------------------------------------
__global__ void hist_k(const int* __restrict__ ei, int E, int n, int* __restrict__ deg) {
    int e = blockIdx.x * 256 + threadIdx.x;
    int ET = E + n;
    if (e >= ET) return;
    int d = (e < E) ? ei[E + e] : (e - E);
    atomicAdd(&deg[d], 1);
}

__global__ void scan1_k(const int* __restrict__ deg, int* __restrict__ incl,
                        int* __restrict__ bsums, int n) {
    __shared__ int s[256];
    int tid = threadIdx.x;
    int i = blockIdx.x * 256 + tid;
    int v = (i < n) ? deg[i] : 0;
    s[tid] = v;
    __syncthreads();
    for (int off = 1; off < 256; off <<= 1) {
        int t = (tid >= off) ? s[tid - off] : 0;
        __syncthreads();
        s[tid] += t;
        __syncthreads();
    }
    if (i < n) incl[i] = s[tid];
    if (tid == 255) bsums[blockIdx.x] = s[255];
}

__global__ void scan2_k(int* __restrict__ bsums, int nch) {
    __shared__ int s[256];
    int tid = threadIdx.x;
    int v = (tid < nch) ? bsums[tid] : 0;
    int orig = v;
    s[tid] = v;
    __syncthreads();
    for (int off = 1; off < 256; off <<= 1) {
        int t = (tid >= off) ? s[tid - off] : 0;
        __syncthreads();
        s[tid] += t;
        __syncthreads();
    }
    if (tid < nch) bsums[tid] = s[tid] - orig;  // exclusive
}

__global__ void scan3_k(int* __restrict__ offsets, int* __restrict__ cursor,
                        const int* __restrict__ bsums, int n, int total) {
    int i = blockIdx.x * 256 + threadIdx.x;
    if (i < n) {
        int excl = offsets[i] - cursor[i] + bsums[i >> 8];
        offsets[i] = excl;
        cursor[i]  = excl;
    }
    if (i == 0 && blockIdx.x == 0) offsets[n] = total;
}

__global__ void fill_k(const int* __restrict__ ei, int E, int n,
                       int* __restrict__ cursor, int* __restrict__ csr) {
    int e = blockIdx.x * 256 + threadIdx.x;
    int ET = E + n;
    if (e >= ET) return;
    int s, d;
    if (e < E) { s = ei[e]; d = ei[E + e]; }
    else       { s = e - E; d = e - E; }
    int pos = atomicAdd(&cursor[d], 1);
    csr[pos] = s;
}

// ---------------------------------------------------------------------------
// fp32 tiled GEMM: C[M,Nc] = A[M,K] @ B[K,Nc]; Nc % 64 == 0, K % 32 == 0
// ---------------------------------------------------------------------------
__global__ __launch_bounds__(256) void gemm64_k(const float* __restrict__ A,
                                                const float* __restrict__ B,
                                                float* __restrict__ Cc,
                                                int M, int K, int Nc) {
    __shared__ float As[32][64];  // [k][m]
    __shared__ float Bs[32][64];  // [k][n]
    int tid = threadIdx.x;
    int tx = tid & 15, ty = tid >> 4;
    int m0 = blockIdx.x << 6, n0 = blockIdx.y << 6;
    float c[4][4] = {};
    for (int k0 = 0; k0 < K; k0 += 32) {
#pragma unroll
        for (int l = 0; l < 2; l++) {
            int f = tid + (l << 8);          // 0..511
            int r = f >> 3, kq = f & 7;
            int gr = m0 + r;
            float4 av = make_float4(0.f, 0.f, 0.f, 0.f);
            if (gr < M) av = *(const float4*)(A + (size_t)gr * K + k0 + (kq << 2));
            As[(kq << 2) + 0][r] = av.x;
            As[(kq << 2) + 1][r] = av.y;
            As[(kq << 2) + 2][r] = av.z;
            As[(kq << 2) + 3][r] = av.w;
            int kk = f >> 4, c4 = f & 15;
            *(float4*)&Bs[kk][c4 << 2] =
                *(const float4*)(B + (size_t)(k0 + kk) * Nc + n0 + (c4 << 2));
        }
        __syncthreads();
#pragma unroll
        for (int kk = 0; kk < 32; kk++) {
            float4 a = *(const float4*)&As[kk][ty << 2];
            float4 b = *(const float4*)&Bs[kk][tx << 2];
            float av4[4] = {a.x, a.y, a.z, a.w};
            float bv4[4] = {b.x, b.y, b.z, b.w};
#pragma unroll
            for (int i = 0; i < 4; i++)
#pragma unroll
                for (int j = 0; j < 4; j++)
                    c[i][j] = fmaf(av4[i], bv4[j], c[i][j]);
        }
        __syncthreads();
    }
#pragma unroll
    for (int i = 0; i < 4; i++) {
        int gr = m0 + (ty << 2) + i;
        if (gr < M) {
            float4 o = make_float4(c[i][0], c[i][1], c[i][2], c[i][3]);
            *(float4*)(Cc + (size_t)gr * Nc + n0 + (tx << 2)) = o;
        }
    }
}

// ---------------------------------------------------------------------------
// attention prep: as[i] = h[i,:]·a_src, ad[i] = h[i,:]·a_dst   (wave per row)
// ---------------------------------------------------------------------------
template <int D>
__global__ void prep_k(const float* __restrict__ h, const float* __restrict__ avs,
                       const float* __restrict__ avd, float* __restrict__ as_o,
                       float* __restrict__ ad_o, int n) {
    int wid = (blockIdx.x << 2) + (threadIdx.x >> 6);
    int lane = threadIdx.x & 63;
    if (wid >= n) return;
    const float* row = h + (size_t)wid * D;
    float s = 0.f, d = 0.f;
#pragma unroll
    for (int u = 0; u < D / 64; u++) {
        float hv = row[u * 64 + lane];
        s = fmaf(hv, avs[u * 64 + lane], s);
        d = fmaf(hv, avd[u * 64 + lane], d);
    }
#pragma unroll
    for (int o = 32; o; o >>= 1) {
        s += __shfl_xor(s, o);
        d += __shfl_xor(d, o);
    }
    if (lane == 0) { as_o[wid] = s; ad_o[wid] = d; }
}

// ---------------------------------------------------------------------------
// fused per-node softmax + aggregation (wave per node)
// LDS-cached logits + 4-way edge-unrolled gather for MLP
// ---------------------------------------------------------------------------
#define DEG_CAP 128

template <int D, bool DO_ELU>
__global__ __launch_bounds__(256) void agg_k(const int* __restrict__ offs,
                                             const int* __restrict__ csr,
                                             const float* __restrict__ asb,
                                             const float* __restrict__ adb,
                                             const float* __restrict__ h,
                                             const float* __restrict__ bias,
                                             float* __restrict__ out, int n) {
    __shared__ float wsh[4][DEG_CAP];
    __shared__ int   jsh[4][DEG_CAP];
    const int wv   = threadIdx.x >> 6;
    const int lane = threadIdx.x & 63;
    const int wid  = (blockIdx.x << 2) + wv;
    const bool active = wid < n;

    int beg = 0, deg = 0;
    float adi = 0.f;
    if (active) {
        beg = offs[wid];
        deg = offs[wid + 1] - beg;
        adi = adb[wid];
    }
    const int degc = deg < DEG_CAP ? deg : DEG_CAP;

    // pass 1: logits (cached part + overflow), running max
    float m = -INFINITY;
    if (active) {
        for (int e = lane; e < degc; e += 64) {
            int j = csr[beg + e];
            float v = asb[j] + adi;
            v = v > 0.f ? v : NEG_SLOPE * v;
            jsh[wv][e] = j;
            wsh[wv][e] = v;
            m = fmaxf(m, v);
        }
        for (int e = DEG_CAP + lane; e < deg; e += 64) {
            float v = asb[csr[beg + e]] + adi;
            v = v > 0.f ? v : NEG_SLOPE * v;
            m = fmaxf(m, v);
        }
#pragma unroll
        for (int o = 32; o; o >>= 1) m = fmaxf(m, __shfl_xor(m, o));
    }

    // pass 2: exp + sum (reads own writes; no cross-lane yet)
    float inv = 0.f;
    if (active) {
        float ssum = 0.f;
        for (int e = lane; e < degc; e += 64) {
            float ww = __expf(wsh[wv][e] - m);
            wsh[wv][e] = ww;
            ssum += ww;
        }
        for (int e = DEG_CAP + lane; e < deg; e += 64) {
            float v = asb[csr[beg + e]] + adi;
            v = v > 0.f ? v : NEG_SLOPE * v;
            ssum += __expf(v - m);
        }
#pragma unroll
        for (int o = 32; o; o >>= 1) ssum += __shfl_xor(ssum, o);
        inv = 1.f / ssum;
    }

    __syncthreads();  // wsh/jsh now read cross-lane

    if (!active) return;

    constexpr int U = D / 64;  // 4 (D=256) or 1 (D=64)
    float a0[U] = {}, a1[U] = {}, a2[U] = {}, a3[U] = {};

    int e = 0;
    for (; e + 4 <= degc; e += 4) {
        int j0 = jsh[wv][e], j1 = jsh[wv][e + 1], j2 = jsh[wv][e + 2], j3 = jsh[wv][e + 3];
        float w0 = wsh[wv][e], w1 = wsh[wv][e + 1], w2 = wsh[wv][e + 2], w3 = wsh[wv][e + 3];
        if constexpr (U == 4) {
            const float4 h0 = *(const float4*)(h + (size_t)j0 * D + (lane << 2));
            const float4 h1 = *(const float4*)(h + (size_t)j1 * D + (lane << 2));
            const float4 h2 = *(const float4*)(h + (size_t)j2 * D + (lane << 2));
            const float4 h3 = *(const float4*)(h + (size_t)j3 * D + (lane << 2));
            a0[0] = fmaf(w0, h0.x, a0[0]); a0[1] = fmaf(w0, h0.y, a0[1]);
            a0[2] = fmaf(w0, h0.z, a0[2]); a0[3] = fmaf(w0, h0.w, a0[3]);
            a1[0] = fmaf(w1, h1.x, a1[0]); a1[1] = fmaf(w1, h1.y, a1[1]);
            a1[2] = fmaf(w1, h1.z, a1[2]); a1[3] = fmaf(w1, h1.w, a1[3]);
            a2[0] = fmaf(w2, h2.x, a2[0]); a2[1] = fmaf(w2, h2.y, a2[1]);
            a2[2] = fmaf(w2, h2.z, a2[2]); a2[3] = fmaf(w2, h2.w, a2[3]);
            a3[0] = fmaf(w3, h3.x, a3[0]); a3[1] = fmaf(w3, h3.y, a3[1]);
            a3[2] = fmaf(w3, h3.z, a3[2]); a3[3] = fmaf(w3, h3.w, a3[3]);
        } else {
            a0[0] = fmaf(w0, h[(size_t)j0 * D + lane], a0[0]);
            a1[0] = fmaf(w1, h[(size_t)j1 * D + lane], a1[0]);
            a2[0] = fmaf(w2, h[(size_t)j2 * D + lane], a2[0]);
            a3[0] = fmaf(w3, h[(size_t)j3 * D + lane], a3[0]);
        }
    }
    for (; e < degc; ++e) {
        int j = jsh[wv][e];
        float ww = wsh[wv][e];
        if constexpr (U == 4) {
            const float4 hv = *(const float4*)(h + (size_t)j * D + (lane << 2));
            a0[0] = fmaf(ww, hv.x, a0[0]); a0[1] = fmaf(ww, hv.y, a0[1]);
            a0[2] = fmaf(ww, hv.z, a0[2]); a0[3] = fmaf(ww, hv.w, a0[3]);
        } else {
            a0[0] = fmaf(ww, h[(size_t)j * D + lane], a0[0]);
        }
    }
    // overflow edges (deg > DEG_CAP): recompute weights (rare slow path)
    for (int eo = DEG_CAP; eo < deg; ++eo) {
        int j = csr[beg + eo];
        float v = asb[j] + adi;
        v = v > 0.f ? v : NEG_SLOPE * v;
        float ww = __expf(v - m);
        if constexpr (U == 4) {
            const float4 hv = *(const float4*)(h + (size_t)j * D + (lane << 2));
            a0[0] = fmaf(ww, hv.x, a0[0]); a0[1] = fmaf(ww, hv.y, a0[1]);
            a0[2] = fmaf(ww, hv.z, a0[2]); a0[3] = fmaf(ww, hv.w, a0[3]);
        } else {
            a0[0] = fmaf(ww, h[(size_t)j * D + lane], a0[0]);
        }
    }

    if constexpr (U == 4) {
        float4 o;
        float* po = &o.x;
#pragma unroll
        for (int u = 0; u < 4; u++) {
            float t = (a0[u] + a1[u] + a2[u] + a3[u]) * inv + bias[(lane << 2) + u];
            if (DO_ELU) t = t > 0.f ? t : expm1f(t);
            po[u] = t;
        }
        *(float4*)(out + (size_t)wid * D + (lane << 2)) = o;
    } else {
        float t = (a0[0] + a1[0] + a2[0] + a3[0]) * inv + bias[lane];
        if (DO_ELU) t = t > 0.f ? t : expm1f(t);
        out[(size_t)wid * D + lane] = t;
    }
}

// ---------------------------------------------------------------------------
// layer 3: h3 = out2 @ W3 (64->1) fused with logit pieces
// ---------------------------------------------------------------------------
__global__ void l3_prep_k(const float* __restrict__ o2, const float* __restrict__ W3,
                          const float* __restrict__ as3, const float* __restrict__ ad3,
                          float* __restrict__ h3, float* __restrict__ asb,
                          float* __restrict__ adb, int n) {
    int wid = (blockIdx.x << 2) + (threadIdx.x >> 6);
    int lane = threadIdx.x & 63;
    if (wid >= n) return;
    float t = o2[(size_t)wid * 64 + lane] * W3[lane];
#pragma unroll
    for (int o = 32; o; o >>= 1) t += __shfl_xor(t, o);
    if (lane == 0) {
        h3[wid]  = t;
        asb[wid] = t * as3[0];
        adb[wid] = t * ad3[0];
    }
}

__global__ void agg3_k(const int* __restrict__ offs, const int* __restrict__ csr,
                       const float* __restrict__ asb, const float* __restrict__ adb,
                       const float* __restrict__ h3, const float* __restrict__ b3,
                       float* __restrict__ out, int n) {
    int wid = (blockIdx.x << 2) + (threadIdx.x >> 6);
    int lane = threadIdx.x & 63;
    if (wid >= n) return;
    int beg = offs[wid], end = offs[wid + 1];
    float adi = adb[wid];

    float m = -INFINITY;
    for (int e = beg + lane; e < end; e += 64) {
        float v = asb[csr[e]] + adi;
        v = v > 0.f ? v : NEG_SLOPE * v;
        m = fmaxf(m, v);
    }
#pragma unroll
    for (int o = 32; o; o >>= 1) m = fmaxf(m, __shfl_xor(m, o));

    float ssum = 0.f, acc = 0.f;
    for (int e = beg + lane; e < end; e += 64) {
        int j = csr[e];
        float v = asb[j] + adi;
        v = v > 0.f ? v : NEG_SLOPE * v;
        float w = __expf(v - m);
        ssum += w;
        acc = fmaf(w, h3[j], acc);
    }
#pragma unroll
    for (int o = 32; o; o >>= 1) {
        ssum += __shfl_xor(ssum, o);
        acc  += __shfl_xor(acc, o);
    }
    if (lane == 0) out[wid] = acc / ssum + b3[0];
}

// ---------------------------------------------------------------------------
extern "C" void kernel_launch(void* const* d_in, const int* in_sizes, int n_in,
                              void* d_out, int out_size, void* d_ws, size_t ws_size,
                              hipStream_t stream) {
    const float* x   = (const float*)d_in[0];
    const int*   ei  = (const int*)d_in[1];
    const float* W1  = (const float*)d_in[2];
    const float* as1 = (const float*)d_in[3];
    const float* ad1 = (const float*)d_in[4];
    const float* b1  = (const float*)d_in[5];
    const float* W2  = (const float*)d_in[6];
    const float* as2 = (const float*)d_in[7];
    const float* ad2 = (const float*)d_in[8];
    const float* b2  = (const float*)d_in[9];
    const float* W3  = (const float*)d_in[10];
    const float* as3 = (const float*)d_in[11];
    const float* ad3 = (const float*)d_in[12];
    const float* b3  = (const float*)d_in[13];

    const int d1 = in_sizes[3];                    // 256
    const int C  = in_sizes[2] / d1;               // 128
    const int N  = in_sizes[0] / C;                // 50000
    const int E  = in_sizes[1] / 2;                // 800000
    const int d2 = in_sizes[7];                    // 64
    const int ET = E + N;                          // 850000

    char* p = (char*)d_ws;
    auto alloc = [&](size_t bytes) -> void* {
        void* q = (void*)p;
        p += (bytes + 255) & ~(size_t)255;
        return q;
    };
    int*   offsets = (int*)alloc(sizeof(int) * (size_t)(N + 1));
    int*   cursor  = (int*)alloc(sizeof(int) * (size_t)N);
    int*   bsums   = (int*)alloc(sizeof(int) * 256);
    int*   csr     = (int*)alloc(sizeof(int) * (size_t)ET);
    float* asb     = (float*)alloc(sizeof(float) * (size_t)N);
    float* adb     = (float*)alloc(sizeof(float) * (size_t)N);
    float* hbuf    = (float*)alloc(sizeof(float) * (size_t)N * d1);
    float* obuf    = (float*)alloc(sizeof(float) * (size_t)N * d1);

    const int eb  = (ET + 255) / 256;
    const int nch = (N + 255) / 256;
    const int wb  = (N + 3) / 4;

    // ---- CSR build ----
    hipMemsetAsync(cursor, 0, sizeof(int) * (size_t)N, stream);
    hist_k<<<eb, 256, 0, stream>>>(ei, E, N, cursor);
    scan1_k<<<nch, 256, 0, stream>>>(cursor, offsets, bsums, N);
    scan2_k<<<1, 256, 0, stream>>>(bsums, nch);
    scan3_k<<<nch, 256, 0, stream>>>(offsets, cursor, bsums, N, ET);
    fill_k<<<eb, 256, 0, stream>>>(ei, E, N, cursor, csr);

    // ---- layer 1: 128 -> 256, ELU ----
    {
        dim3 g((N + 63) / 64, d1 / 64);
        gemm64_k<<<g, 256, 0, stream>>>(x, W1, hbuf, N, C, d1);
        prep_k<256><<<wb, 256, 0, stream>>>(hbuf, as1, ad1, asb, adb, N);
        agg_k<256, true><<<wb, 256, 0, stream>>>(offsets, csr, asb, adb, hbuf, b1, obuf, N);
    }
    // ---- layer 2: 256 -> 64, ELU ----
    {
        dim3 g((N + 63) / 64, d2 / 64);
        gemm64_k<<<g, 256, 0, stream>>>(obuf, W2, hbuf, N, d1, d2);
        prep_k<64><<<wb, 256, 0, stream>>>(hbuf, as2, ad2, asb, adb, N);
        agg_k<64, true><<<wb, 256, 0, stream>>>(offsets, csr, asb, adb, hbuf, b2, obuf, N);
    }
    // ---- layer 3: 64 -> 1 ----
    {
        l3_prep_k<<<wb, 256, 0, stream>>>(obuf, W3, as3, ad3, hbuf, asb, adb, N);
        agg3_k<<<wb, 256, 0, stream>>>(offsets, csr, asb, adb, hbuf, b3, (float*)d_out, N);
    }
}

// Round 3
// 388.528 us; speedup vs baseline: 1.3773x; 1.2121x over previous
//
#include <hip/hip_runtime.h>
#include <hip/hip_bf16.h>
#include <hip/hip_fp16.h>
#include <math.h>

#define NEG_SLOPE 0.2f

typedef __attribute__((ext_vector_type(8))) short bf16x8_t;
typedef __attribute__((ext_vector_type(4))) float f32x4_t;

struct __align__(8) half4_t { __half2 a, b; };

// ---------------------------------------------------------------------------
// CSR build: histogram -> block scan -> scatter fill
// ---------------------------------------------------------------------------
__global__ void hist_k(const int* __restrict__ ei, int E, int n, int* __restrict__ deg) {
    int e = blockIdx.x * 256 + threadIdx.x;
    int ET = E + n;
    if (e >= ET) return;
    int d = (e < E) ? ei[E + e] : (e - E);
    atomicAdd(&deg[d], 1);
}

__global__ void scan1_k(const int* __restrict__ deg, int* __restrict__ incl,
                        int* __restrict__ bsums, int n) {
    __shared__ int s[256];
    int tid = threadIdx.x;
    int i = blockIdx.x * 256 + tid;
    int v = (i < n) ? deg[i] : 0;
    s[tid] = v;
    __syncthreads();
    for (int off = 1; off < 256; off <<= 1) {
        int t = (tid >= off) ? s[tid - off] : 0;
        __syncthreads();
        s[tid] += t;
        __syncthreads();
    }
    if (i < n) incl[i] = s[tid];
    if (tid == 255) bsums[blockIdx.x] = s[255];
}

__global__ void scan2_k(int* __restrict__ bsums, int nch) {
    __shared__ int s[256];
    int tid = threadIdx.x;
    int v = (tid < nch) ? bsums[tid] : 0;
    int orig = v;
    s[tid] = v;
    __syncthreads();
    for (int off = 1; off < 256; off <<= 1) {
        int t = (tid >= off) ? s[tid - off] : 0;
        __syncthreads();
        s[tid] += t;
        __syncthreads();
    }
    if (tid < nch) bsums[tid] = s[tid] - orig;  // exclusive
}

__global__ void scan3_k(int* __restrict__ offsets, int* __restrict__ cursor,
                        const int* __restrict__ bsums, int n, int total) {
    int i = blockIdx.x * 256 + threadIdx.x;
    if (i < n) {
        int excl = offsets[i] - cursor[i] + bsums[i >> 8];
        offsets[i] = excl;
        cursor[i]  = excl;
    }
    if (i == 0 && blockIdx.x == 0) offsets[n] = total;
}

__global__ void fill_k(const int* __restrict__ ei, int E, int n,
                       int* __restrict__ cursor, int* __restrict__ csr) {
    int e = blockIdx.x * 256 + threadIdx.x;
    int ET = E + n;
    if (e >= ET) return;
    int s, d;
    if (e < E) { s = ei[e]; d = ei[E + e]; }
    else       { s = e - E; d = e - E; }
    int pos = atomicAdd(&cursor[d], 1);
    csr[pos] = s;
}

// ---------------------------------------------------------------------------
// split-bf16 MFMA GEMM: C = A(fp32)[M,K] @ B(fp32)[K,Nc]
// 3-term split: Ahi*Bhi + Ahi*Blo + Alo*Bhi  (error ~2^-18 relative)
// block tile 128x64, 4 waves (2x2), wave tile 64x32, BK=32
// also writes fp16 copy Ch for the gather consumer
// ---------------------------------------------------------------------------
__device__ inline void bf16_split(float f, ushort& hi, ushort& lo) {
    unsigned int u = __float_as_uint(f);
    unsigned int r = u + 0x7FFFu + ((u >> 16) & 1u);
    hi = (ushort)(r >> 16);
    float back = __uint_as_float((unsigned int)hi << 16);
    float rem = f - back;
    unsigned int u2 = __float_as_uint(rem);
    unsigned int r2 = u2 + 0x7FFFu + ((u2 >> 16) & 1u);
    lo = (ushort)(r2 >> 16);
}

__global__ __launch_bounds__(256) void gemm_split_k(const float* __restrict__ A,
                                                    const float* __restrict__ B,
                                                    float* __restrict__ C,
                                                    __half* __restrict__ Ch,
                                                    int M, int K, int Nc) {
    __shared__ __align__(16) ushort sAh[128][40];
    __shared__ __align__(16) ushort sAl[128][40];
    __shared__ __align__(16) ushort sBh[64][40];
    __shared__ __align__(16) ushort sBl[64][40];

    const int tid  = threadIdx.x;
    const int lane = tid & 63;
    const int wv   = tid >> 6;
    const int wm   = wv & 1, wn = wv >> 1;
    const int m0   = blockIdx.x << 7;
    const int n0   = blockIdx.y << 6;

    f32x4_t acc[4][2];
#pragma unroll
    for (int i = 0; i < 4; i++)
#pragma unroll
        for (int j = 0; j < 2; j++) acc[i][j] = (f32x4_t){0.f, 0.f, 0.f, 0.f};

    const int arow = tid >> 1;          // 0..127
    const int acb  = (tid & 1) << 4;    // 0 / 16
    const int bcol = tid & 63;
    const int bkb  = (tid >> 6) << 3;   // 0,8,16,24

    for (int k0 = 0; k0 < K; k0 += 32) {
        // ---- stage A (128x32 fp32 -> hi/lo bf16) ----
        {
            float fv[16];
            const int gr = m0 + arow;
            if (gr < M) {
                const float* ap = A + (size_t)gr * K + k0 + acb;
#pragma unroll
                for (int q = 0; q < 4; q++) {
                    float4 t = *(const float4*)(ap + (q << 2));
                    fv[q * 4 + 0] = t.x; fv[q * 4 + 1] = t.y;
                    fv[q * 4 + 2] = t.z; fv[q * 4 + 3] = t.w;
                }
            } else {
#pragma unroll
                for (int q = 0; q < 16; q++) fv[q] = 0.f;
            }
            ushort hv[16], lv[16];
#pragma unroll
            for (int q = 0; q < 16; q++) bf16_split(fv[q], hv[q], lv[q]);
            *(bf16x8_t*)&sAh[arow][acb]     = *(bf16x8_t*)&hv[0];
            *(bf16x8_t*)&sAh[arow][acb + 8] = *(bf16x8_t*)&hv[8];
            *(bf16x8_t*)&sAl[arow][acb]     = *(bf16x8_t*)&lv[0];
            *(bf16x8_t*)&sAl[arow][acb + 8] = *(bf16x8_t*)&lv[8];
        }
        // ---- stage B (32x64 fp32 -> transposed hi/lo bf16) ----
        {
            float fv[8];
#pragma unroll
            for (int j = 0; j < 8; j++)
                fv[j] = B[(size_t)(k0 + bkb + j) * Nc + n0 + bcol];
            ushort hv[8], lv[8];
#pragma unroll
            for (int j = 0; j < 8; j++) bf16_split(fv[j], hv[j], lv[j]);
            *(bf16x8_t*)&sBh[bcol][bkb] = *(bf16x8_t*)&hv[0];
            *(bf16x8_t*)&sBl[bcol][bkb] = *(bf16x8_t*)&lv[0];
        }
        __syncthreads();
        // ---- MFMA ----
        bf16x8_t ah[4], al[4], bh[2], bl[2];
        const int rbase = (wm << 6) + (lane & 15);
        const int slot  = (lane >> 4) << 3;
#pragma unroll
        for (int mi = 0; mi < 4; mi++) {
            ah[mi] = *(const bf16x8_t*)&sAh[rbase + (mi << 4)][slot];
            al[mi] = *(const bf16x8_t*)&sAl[rbase + (mi << 4)][slot];
        }
        const int cbase = (wn << 5) + (lane & 15);
#pragma unroll
        for (int ni = 0; ni < 2; ni++) {
            bh[ni] = *(const bf16x8_t*)&sBh[cbase + (ni << 4)][slot];
            bl[ni] = *(const bf16x8_t*)&sBl[cbase + (ni << 4)][slot];
        }
#pragma unroll
        for (int mi = 0; mi < 4; mi++)
#pragma unroll
            for (int ni = 0; ni < 2; ni++) {
                acc[mi][ni] = __builtin_amdgcn_mfma_f32_16x16x32_bf16(ah[mi], bh[ni], acc[mi][ni], 0, 0, 0);
                acc[mi][ni] = __builtin_amdgcn_mfma_f32_16x16x32_bf16(ah[mi], bl[ni], acc[mi][ni], 0, 0, 0);
                acc[mi][ni] = __builtin_amdgcn_mfma_f32_16x16x32_bf16(al[mi], bh[ni], acc[mi][ni], 0, 0, 0);
            }
        __syncthreads();
    }
    // ---- epilogue: C/D layout col=lane&15, row=(lane>>4)*4+reg ----
#pragma unroll
    for (int mi = 0; mi < 4; mi++)
#pragma unroll
        for (int ni = 0; ni < 2; ni++) {
            int row = m0 + (wm << 6) + (mi << 4) + ((lane >> 4) << 2);
            int col = n0 + (wn << 5) + (ni << 4) + (lane & 15);
#pragma unroll
            for (int r = 0; r < 4; r++) {
                if (row + r < M) {
                    float v = acc[mi][ni][r];
                    C[(size_t)(row + r) * Nc + col]  = v;
                    Ch[(size_t)(row + r) * Nc + col] = __float2half(v);
                }
            }
        }
}

// ---------------------------------------------------------------------------
// attention prep: as[i] = h[i,:]·a_src, ad[i] = h[i,:]·a_dst   (wave per row)
// ---------------------------------------------------------------------------
template <int D>
__global__ void prep_k(const float* __restrict__ h, const float* __restrict__ avs,
                       const float* __restrict__ avd, float* __restrict__ as_o,
                       float* __restrict__ ad_o, int n) {
    int wid = (blockIdx.x << 2) + (threadIdx.x >> 6);
    int lane = threadIdx.x & 63;
    if (wid >= n) return;
    const float* row = h + (size_t)wid * D;
    float s = 0.f, d = 0.f;
#pragma unroll
    for (int u = 0; u < D / 64; u++) {
        float hv = row[u * 64 + lane];
        s = fmaf(hv, avs[u * 64 + lane], s);
        d = fmaf(hv, avd[u * 64 + lane], d);
    }
#pragma unroll
    for (int o = 32; o; o >>= 1) {
        s += __shfl_xor(s, o);
        d += __shfl_xor(d, o);
    }
    if (lane == 0) { as_o[wid] = s; ad_o[wid] = d; }
}

// ---------------------------------------------------------------------------
// fused per-node softmax + aggregation (wave per node), fp16 h gather
// ---------------------------------------------------------------------------
#define DEG_CAP 128

template <int D, bool DO_ELU>
__global__ __launch_bounds__(256) void agg_k(const int* __restrict__ offs,
                                             const int* __restrict__ csr,
                                             const float* __restrict__ asb,
                                             const float* __restrict__ adb,
                                             const __half* __restrict__ h,
                                             const float* __restrict__ bias,
                                             float* __restrict__ out, int n) {
    __shared__ float wsh[4][DEG_CAP];
    __shared__ int   jsh[4][DEG_CAP];
    const int wv   = threadIdx.x >> 6;
    const int lane = threadIdx.x & 63;
    const int wid  = (blockIdx.x << 2) + wv;
    const bool active = wid < n;

    int beg = 0, deg = 0;
    float adi = 0.f;
    if (active) {
        beg = offs[wid];
        deg = offs[wid + 1] - beg;
        adi = adb[wid];
    }
    const int degc = deg < DEG_CAP ? deg : DEG_CAP;

    float m = -INFINITY;
    if (active) {
        for (int e = lane; e < degc; e += 64) {
            int j = csr[beg + e];
            float v = asb[j] + adi;
            v = v > 0.f ? v : NEG_SLOPE * v;
            jsh[wv][e] = j;
            wsh[wv][e] = v;
            m = fmaxf(m, v);
        }
        for (int e = DEG_CAP + lane; e < deg; e += 64) {
            float v = asb[csr[beg + e]] + adi;
            v = v > 0.f ? v : NEG_SLOPE * v;
            m = fmaxf(m, v);
        }
#pragma unroll
        for (int o = 32; o; o >>= 1) m = fmaxf(m, __shfl_xor(m, o));
    }

    float inv = 0.f;
    if (active) {
        float ssum = 0.f;
        for (int e = lane; e < degc; e += 64) {
            float ww = __expf(wsh[wv][e] - m);
            wsh[wv][e] = ww;
            ssum += ww;
        }
        for (int e = DEG_CAP + lane; e < deg; e += 64) {
            float v = asb[csr[beg + e]] + adi;
            v = v > 0.f ? v : NEG_SLOPE * v;
            ssum += __expf(v - m);
        }
#pragma unroll
        for (int o = 32; o; o >>= 1) ssum += __shfl_xor(ssum, o);
        inv = 1.f / ssum;
    }

    __syncthreads();

    if (!active) return;

    constexpr int U = D / 64;  // 4 (D=256) or 1 (D=64)
    float a0[U] = {}, a1[U] = {}, a2[U] = {}, a3[U] = {};

    int e = 0;
    for (; e + 4 <= degc; e += 4) {
        int j0 = jsh[wv][e], j1 = jsh[wv][e + 1], j2 = jsh[wv][e + 2], j3 = jsh[wv][e + 3];
        float w0 = wsh[wv][e], w1 = wsh[wv][e + 1], w2 = wsh[wv][e + 2], w3 = wsh[wv][e + 3];
        if constexpr (U == 4) {
            const half4_t h0 = *(const half4_t*)(h + (size_t)j0 * D + (lane << 2));
            const half4_t h1 = *(const half4_t*)(h + (size_t)j1 * D + (lane << 2));
            const half4_t h2 = *(const half4_t*)(h + (size_t)j2 * D + (lane << 2));
            const half4_t h3 = *(const half4_t*)(h + (size_t)j3 * D + (lane << 2));
            float2 f0a = __half22float2(h0.a), f0b = __half22float2(h0.b);
            float2 f1a = __half22float2(h1.a), f1b = __half22float2(h1.b);
            float2 f2a = __half22float2(h2.a), f2b = __half22float2(h2.b);
            float2 f3a = __half22float2(h3.a), f3b = __half22float2(h3.b);
            a0[0] = fmaf(w0, f0a.x, a0[0]); a0[1] = fmaf(w0, f0a.y, a0[1]);
            a0[2] = fmaf(w0, f0b.x, a0[2]); a0[3] = fmaf(w0, f0b.y, a0[3]);
            a1[0] = fmaf(w1, f1a.x, a1[0]); a1[1] = fmaf(w1, f1a.y, a1[1]);
            a1[2] = fmaf(w1, f1b.x, a1[2]); a1[3] = fmaf(w1, f1b.y, a1[3]);
            a2[0] = fmaf(w2, f2a.x, a2[0]); a2[1] = fmaf(w2, f2a.y, a2[1]);
            a2[2] = fmaf(w2, f2b.x, a2[2]); a2[3] = fmaf(w2, f2b.y, a2[3]);
            a3[0] = fmaf(w3, f3a.x, a3[0]); a3[1] = fmaf(w3, f3a.y, a3[1]);
            a3[2] = fmaf(w3, f3b.x, a3[2]); a3[3] = fmaf(w3, f3b.y, a3[3]);
        } else {
            a0[0] = fmaf(w0, __half2float(h[(size_t)j0 * D + lane]), a0[0]);
            a1[0] = fmaf(w1, __half2float(h[(size_t)j1 * D + lane]), a1[0]);
            a2[0] = fmaf(w2, __half2float(h[(size_t)j2 * D + lane]), a2[0]);
            a3[0] = fmaf(w3, __half2float(h[(size_t)j3 * D + lane]), a3[0]);
        }
    }
    for (; e < degc; ++e) {
        int j = jsh[wv][e];
        float ww = wsh[wv][e];
        if constexpr (U == 4) {
            const half4_t hv = *(const half4_t*)(h + (size_t)j * D + (lane << 2));
            float2 fa = __half22float2(hv.a), fb = __half22float2(hv.b);
            a0[0] = fmaf(ww, fa.x, a0[0]); a0[1] = fmaf(ww, fa.y, a0[1]);
            a0[2] = fmaf(ww, fb.x, a0[2]); a0[3] = fmaf(ww, fb.y, a0[3]);
        } else {
            a0[0] = fmaf(ww, __half2float(h[(size_t)j * D + lane]), a0[0]);
        }
    }
    for (int eo = DEG_CAP; eo < deg; ++eo) {
        int j = csr[beg + eo];
        float v = asb[j] + adi;
        v = v > 0.f ? v : NEG_SLOPE * v;
        float ww = __expf(v - m);
        if constexpr (U == 4) {
            const half4_t hv = *(const half4_t*)(h + (size_t)j * D + (lane << 2));
            float2 fa = __half22float2(hv.a), fb = __half22float2(hv.b);
            a0[0] = fmaf(ww, fa.x, a0[0]); a0[1] = fmaf(ww, fa.y, a0[1]);
            a0[2] = fmaf(ww, fb.x, a0[2]); a0[3] = fmaf(ww, fb.y, a0[3]);
        } else {
            a0[0] = fmaf(ww, __half2float(h[(size_t)j * D + lane]), a0[0]);
        }
    }

    if constexpr (U == 4) {
        float4 o;
        float* po = &o.x;
#pragma unroll
        for (int u = 0; u < 4; u++) {
            float t = (a0[u] + a1[u] + a2[u] + a3[u]) * inv + bias[(lane << 2) + u];
            if (DO_ELU) t = t > 0.f ? t : expm1f(t);
            po[u] = t;
        }
        *(float4*)(out + (size_t)wid * D + (lane << 2)) = o;
    } else {
        float t = (a0[0] + a1[0] + a2[0] + a3[0]) * inv + bias[lane];
        if (DO_ELU) t = t > 0.f ? t : expm1f(t);
        out[(size_t)wid * D + lane] = t;
    }
}

// ---------------------------------------------------------------------------
// layer 3: h3 = out2 @ W3 (64->1) fused with logit pieces
// ---------------------------------------------------------------------------
__global__ void l3_prep_k(const float* __restrict__ o2, const float* __restrict__ W3,
                          const float* __restrict__ as3, const float* __restrict__ ad3,
                          float* __restrict__ h3, float* __restrict__ asb,
                          float* __restrict__ adb, int n) {
    int wid = (blockIdx.x << 2) + (threadIdx.x >> 6);
    int lane = threadIdx.x & 63;
    if (wid >= n) return;
    float t = o2[(size_t)wid * 64 + lane] * W3[lane];
#pragma unroll
    for (int o = 32; o; o >>= 1) t += __shfl_xor(t, o);
    if (lane == 0) {
        h3[wid]  = t;
        asb[wid] = t * as3[0];
        adb[wid] = t * ad3[0];
    }
}

__global__ void agg3_k(const int* __restrict__ offs, const int* __restrict__ csr,
                       const float* __restrict__ asb, const float* __restrict__ adb,
                       const float* __restrict__ h3, const float* __restrict__ b3,
                       float* __restrict__ out, int n) {
    int wid = (blockIdx.x << 2) + (threadIdx.x >> 6);
    int lane = threadIdx.x & 63;
    if (wid >= n) return;
    int beg = offs[wid], end = offs[wid + 1];
    float adi = adb[wid];

    float m = -INFINITY;
    for (int e = beg + lane; e < end; e += 64) {
        float v = asb[csr[e]] + adi;
        v = v > 0.f ? v : NEG_SLOPE * v;
        m = fmaxf(m, v);
    }
#pragma unroll
    for (int o = 32; o; o >>= 1) m = fmaxf(m, __shfl_xor(m, o));

    float ssum = 0.f, acc = 0.f;
    for (int e = beg + lane; e < end; e += 64) {
        int j = csr[e];
        float v = asb[j] + adi;
        v = v > 0.f ? v : NEG_SLOPE * v;
        float w = __expf(v - m);
        ssum += w;
        acc = fmaf(w, h3[j], acc);
    }
#pragma unroll
    for (int o = 32; o; o >>= 1) {
        ssum += __shfl_xor(ssum, o);
        acc  += __shfl_xor(acc, o);
    }
    if (lane == 0) out[wid] = acc / ssum + b3[0];
}

// ---------------------------------------------------------------------------
extern "C" void kernel_launch(void* const* d_in, const int* in_sizes, int n_in,
                              void* d_out, int out_size, void* d_ws, size_t ws_size,
                              hipStream_t stream) {
    const float* x   = (const float*)d_in[0];
    const int*   ei  = (const int*)d_in[1];
    const float* W1  = (const float*)d_in[2];
    const float* as1 = (const float*)d_in[3];
    const float* ad1 = (const float*)d_in[4];
    const float* b1  = (const float*)d_in[5];
    const float* W2  = (const float*)d_in[6];
    const float* as2 = (const float*)d_in[7];
    const float* ad2 = (const float*)d_in[8];
    const float* b2  = (const float*)d_in[9];
    const float* W3  = (const float*)d_in[10];
    const float* as3 = (const float*)d_in[11];
    const float* ad3 = (const float*)d_in[12];
    const float* b3  = (const float*)d_in[13];

    const int d1 = in_sizes[3];                    // 256
    const int C  = in_sizes[2] / d1;               // 128
    const int N  = in_sizes[0] / C;                // 50000
    const int E  = in_sizes[1] / 2;                // 800000
    const int d2 = in_sizes[7];                    // 64
    const int ET = E + N;                          // 850000

    char* p = (char*)d_ws;
    auto alloc = [&](size_t bytes) -> void* {
        void* q = (void*)p;
        p += (bytes + 255) & ~(size_t)255;
        return q;
    };
    int*    offsets = (int*)alloc(sizeof(int) * (size_t)(N + 1));
    int*    cursor  = (int*)alloc(sizeof(int) * (size_t)N);
    int*    bsums   = (int*)alloc(sizeof(int) * 256);
    int*    csr     = (int*)alloc(sizeof(int) * (size_t)ET);
    float*  asb     = (float*)alloc(sizeof(float) * (size_t)N);
    float*  adb     = (float*)alloc(sizeof(float) * (size_t)N);
    float*  hbuf    = (float*)alloc(sizeof(float) * (size_t)N * d1);
    float*  obuf    = (float*)alloc(sizeof(float) * (size_t)N * d1);
    __half* hhalf   = (__half*)alloc(sizeof(__half) * (size_t)N * d1);

    const int eb  = (ET + 255) / 256;
    const int nch = (N + 255) / 256;
    const int wb  = (N + 3) / 4;

    // ---- CSR build ----
    hipMemsetAsync(cursor, 0, sizeof(int) * (size_t)N, stream);
    hist_k<<<eb, 256, 0, stream>>>(ei, E, N, cursor);
    scan1_k<<<nch, 256, 0, stream>>>(cursor, offsets, bsums, N);
    scan2_k<<<1, 256, 0, stream>>>(bsums, nch);
    scan3_k<<<nch, 256, 0, stream>>>(offsets, cursor, bsums, N, ET);
    fill_k<<<eb, 256, 0, stream>>>(ei, E, N, cursor, csr);

    // ---- layer 1: 128 -> 256, ELU ----
    {
        dim3 g((N + 127) / 128, d1 / 64);
        gemm_split_k<<<g, 256, 0, stream>>>(x, W1, hbuf, hhalf, N, C, d1);
        prep_k<256><<<wb, 256, 0, stream>>>(hbuf, as1, ad1, asb, adb, N);
        agg_k<256, true><<<wb, 256, 0, stream>>>(offsets, csr, asb, adb, hhalf, b1, obuf, N);
    }
    // ---- layer 2: 256 -> 64, ELU ----
    {
        dim3 g((N + 127) / 128, d2 / 64);
        gemm_split_k<<<g, 256, 0, stream>>>(obuf, W2, hbuf, hhalf, N, d1, d2);
        prep_k<64><<<wb, 256, 0, stream>>>(hbuf, as2, ad2, asb, adb, N);
        agg_k<64, true><<<wb, 256, 0, stream>>>(offsets, csr, asb, adb, hhalf, b2, obuf, N);
    }
    // ---- layer 3: 64 -> 1 ----
    {
        l3_prep_k<<<wb, 256, 0, stream>>>(obuf, W3, as3, ad3, hbuf, asb, adb, N);
        agg3_k<<<wb, 256, 0, stream>>>(offsets, csr, asb, adb, hbuf, b3, (float*)d_out, N);
    }
}